// Round 7
// baseline (773.776 us; speedup 1.0000x reference)
//
#include <hip/hip_runtime.h>
#include <hip/hip_cooperative_groups.h>

namespace cg = cooperative_groups;

#define B_DIM 64
#define C_DIM 768
#define HID_DIM 768
#define PLANE 576          // 24*24 floats per channel plane
#define PLANE4 144         // float4 per plane
#define KC 48              // k-chunk for FC phases
#define OT 64              // o-tile for FC phases
#define NBLK 1024          // cooperative grid (4 blocks/CU on 256 CUs)

__device__ __forceinline__ float hatcdf(float t) {
    // 0 for t<=-1, 0.5(t+1)^2 for -1<t<=0, 1-0.5(1-t)^2 for 0<t<=1, 1 for t>1
    float u = fminf(fmaxf(t, -1.f), 1.f);
    float a = u + 1.f;
    float b = 1.f - u;
    return (t <= 0.f) ? 0.5f * a * a : 1.f - 0.5f * b * b;
}

// -------- shared helpers for the FC phases (used by fused + fallback) -------
// As/Ws staging + 4x4 register-blocked partial GEMM, atomicAdd into Out.
template <bool RELU_IN>
__device__ __forceinline__ void fc_phase(
    const float* __restrict__ A, const float* __restrict__ bias,
    const float* __restrict__ Wm, float* __restrict__ Out,
    float* __restrict__ As /*[KC][68]*/, float* __restrict__ Ws /*[KC][68]*/,
    int t, int ot, int kc)
{
    #pragma unroll
    for (int j = t; j < B_DIM * (KC / 4); j += 256) {
        const int bb = j / (KC / 4);
        const int k4 = (j % (KC / 4)) * 4;
        float4 v = *reinterpret_cast<const float4*>(A + (size_t)bb * HID_DIM + kc + k4);
        if constexpr (RELU_IN) {
            const float4 bv = *reinterpret_cast<const float4*>(bias + kc + k4);
            v.x = fmaxf(v.x + bv.x, 0.f);
            v.y = fmaxf(v.y + bv.y, 0.f);
            v.z = fmaxf(v.z + bv.z, 0.f);
            v.w = fmaxf(v.w + bv.w, 0.f);
        }
        As[(k4 + 0) * 68 + bb] = v.x;
        As[(k4 + 1) * 68 + bb] = v.y;
        As[(k4 + 2) * 68 + bb] = v.z;
        As[(k4 + 3) * 68 + bb] = v.w;
    }
    #pragma unroll
    for (int j = t; j < KC * (OT / 4); j += 256) {
        const int k = j / (OT / 4);
        const int oo = (j % (OT / 4)) * 4;
        const float4 v = *reinterpret_cast<const float4*>(Wm + (size_t)(kc + k) * HID_DIM + ot + oo);
        *reinterpret_cast<float4*>(&Ws[k * 68 + oo]) = v;
    }
    __syncthreads();

    const int b0 = (t >> 4) * 4;
    const int o0 = (t & 15) * 4;
    float acc[4][4] = {};
    #pragma unroll 6
    for (int k = 0; k < KC; ++k) {
        const float4 a = *reinterpret_cast<const float4*>(&As[k * 68 + b0]);
        const float4 w = *reinterpret_cast<const float4*>(&Ws[k * 68 + o0]);
        acc[0][0] += a.x * w.x; acc[0][1] += a.x * w.y; acc[0][2] += a.x * w.z; acc[0][3] += a.x * w.w;
        acc[1][0] += a.y * w.x; acc[1][1] += a.y * w.y; acc[1][2] += a.y * w.z; acc[1][3] += a.y * w.w;
        acc[2][0] += a.z * w.x; acc[2][1] += a.z * w.y; acc[2][2] += a.z * w.z; acc[2][3] += a.z * w.w;
        acc[3][0] += a.w * w.x; acc[3][1] += a.w * w.y; acc[3][2] += a.w * w.z; acc[3][3] += a.w * w.w;
    }
    #pragma unroll
    for (int i = 0; i < 4; ++i)
        #pragma unroll
        for (int j = 0; j < 4; ++j)
            atomicAdd(&Out[(size_t)(b0 + i) * HID_DIM + ot + o0 + j], acc[i][j]);
}

// pool for one (b, c0..c0+NP-1) strip; weights already in LDS.
template <int NP>
__device__ __forceinline__ void pool_strip(
    const float* __restrict__ X, int b, int c0, int lane,
    const float* __restrict__ wx, const float* __restrict__ wy,
    float sscale, float* __restrict__ feat)
{
    const float4* __restrict__ P =
        reinterpret_cast<const float4*>(X + ((size_t)b * C_DIM + c0) * PLANE);
    float acc[NP];
    #pragma unroll
    for (int r = 0; r < NP; ++r) acc[r] = 0.f;
    #pragma unroll
    for (int r = 0; r < NP; ++r) {
        const float4* __restrict__ Q = P + r * PLANE4;
        int f = lane;
        float4 v = Q[f];
        int h = f / 6, wb = (f - h * 6) * 4;
        acc[r] += wy[h] * (v.x * wx[wb] + v.y * wx[wb + 1] + v.z * wx[wb + 2] + v.w * wx[wb + 3]);
        f = lane + 64;
        v = Q[f];
        h = f / 6; wb = (f - h * 6) * 4;
        acc[r] += wy[h] * (v.x * wx[wb] + v.y * wx[wb + 1] + v.z * wx[wb + 2] + v.w * wx[wb + 3]);
        if (lane < 16) {
            f = lane + 128;
            v = Q[f];
            h = f / 6; wb = (f - h * 6) * 4;
            acc[r] += wy[h] * (v.x * wx[wb] + v.y * wx[wb + 1] + v.z * wx[wb + 2] + v.w * wx[wb + 3]);
        }
    }
    #pragma unroll
    for (int r = 0; r < NP; ++r) {
        float a = acc[r];
        #pragma unroll
        for (int off = 32; off; off >>= 1) a += __shfl_down(a, off);
        if (lane == 0) feat[(size_t)b * C_DIM + c0 + r] = a * sscale;
    }
}

// ---------------- fused single-dispatch cooperative kernel ------------------
__global__ __launch_bounds__(256, 4) void fused_kernel(
    const float* __restrict__ X, const float* __restrict__ box,
    const float* __restrict__ w1, const float* __restrict__ b1,
    const float* __restrict__ w2, const float* __restrict__ b2,
    const float* __restrict__ w3, const float* __restrict__ b3,
    float* __restrict__ out, float* __restrict__ ws)
{
    __shared__ float lds[2 * KC * 68];   // 26 KB; phases reuse it
    float* feat  = ws;
    float* x1raw = feat + B_DIM * HID_DIM;
    float* x2raw = x1raw + B_DIM * HID_DIM;

    const int t = threadIdx.x;
    const int bx = blockIdx.x;
    cg::grid_group grid = cg::this_grid();

    // ---- phase 0+1: zero accumulators, pool ----
    if (bx < 96) {  // 96*256 float4 = 98304 floats = x1raw..x2raw
        reinterpret_cast<float4*>(x1raw)[bx * 256 + t] = make_float4(0.f, 0.f, 0.f, 0.f);
    }
    {
        const int b = bx >> 4;            // 16 blocks per batch
        float* wx = lds;                  // [24]
        float* wy = lds + 24;             // [24]
        float* ss = lds + 48;             // [1]
        if (t < 49) {
            const float x0 = box[b * 4 + 0] * 24.f;
            const float y0 = box[b * 4 + 1] * 24.f;
            const float x1 = box[b * 4 + 2] * 24.f;
            const float y1 = box[b * 4 + 3] * 24.f;
            if (t < 24) {
                wx[t] = hatcdf(x1 - (float)t) - hatcdf(x0 - (float)t);
            } else if (t < 48) {
                const int h = t - 24;
                wy[h] = hatcdf(y1 - (float)h) - hatcdf(y0 - (float)h);
            } else {
                const float bw = (x1 - x0) * 0.25f;
                const float bh = (y1 - y0) * 0.25f;
                const float area = bw * bh;
                ss[0] = (area > 0.f) ? 1.f / (16.f * fmaxf(area, 1e-12f)) : 0.f;
            }
        }
        __syncthreads();
        const int wave = t >> 6;
        const int lane = t & 63;
        const int c0 = (bx & 15) * 48 + wave * 12;   // 12 planes per wave
        pool_strip<12>(X, b, c0, lane, wx, wy, ss[0], feat);
    }
    __threadfence();
    grid.sync();

    // ---- phase 2: fc1 (192 active blocks) ----
    if (bx < (HID_DIM / OT) * (HID_DIM / KC)) {      // 12*16 = 192
        const int ot = (bx % (HID_DIM / OT)) * OT;
        const int kc = (bx / (HID_DIM / OT)) * KC;
        fc_phase<false>(feat, b1, w1, x1raw, lds, lds + KC * 68, t, ot, kc);
    }
    __threadfence();
    grid.sync();

    // ---- phase 3: fc2 with fused relu(x1+b1) ----
    if (bx < (HID_DIM / OT) * (HID_DIM / KC)) {
        const int ot = (bx % (HID_DIM / OT)) * OT;
        const int kc = (bx / (HID_DIM / OT)) * KC;
        fc_phase<true>(x1raw, b1, w2, x2raw, lds, lds + KC * 68, t, ot, kc);
    }
    __threadfence();
    grid.sync();

    // ---- phase 4: head (64 active blocks) ----
    if (bx < B_DIM) {
        const int b = bx;
        float acc = 0.f;
        for (int o = t; o < HID_DIM; o += 256)
            acc += fmaxf(x2raw[(size_t)b * HID_DIM + o] + b2[o], 0.f) * w3[o];
        #pragma unroll
        for (int off = 32; off; off >>= 1) acc += __shfl_down(acc, off);
        float* r = lds;
        if ((t & 63) == 0) r[t >> 6] = acc;
        __syncthreads();
        if (t == 0) out[b] = r[0] + r[1] + r[2] + r[3] + b3[0];
    }
}

// ---------------- fallback path (round-6 proven 4-kernel chain) -------------
__global__ __launch_bounds__(256) void pool_kernel(
    const float* __restrict__ X, const float* __restrict__ box,
    float* __restrict__ feat, float* __restrict__ zbuf)
{
    const int t = threadIdx.x;
    const int bx = blockIdx.x;
    if (bx < 96) {
        reinterpret_cast<float4*>(zbuf)[bx * 256 + t] = make_float4(0.f, 0.f, 0.f, 0.f);
    }
    const int b = bx >> 5;
    __shared__ float wx[24], wy[24];
    __shared__ float sscale;
    if (t < 49) {
        const float x0 = box[b * 4 + 0] * 24.f;
        const float y0 = box[b * 4 + 1] * 24.f;
        const float x1 = box[b * 4 + 2] * 24.f;
        const float y1 = box[b * 4 + 3] * 24.f;
        if (t < 24) {
            wx[t] = hatcdf(x1 - (float)t) - hatcdf(x0 - (float)t);
        } else if (t < 48) {
            const int h = t - 24;
            wy[h] = hatcdf(y1 - (float)h) - hatcdf(y0 - (float)h);
        } else {
            const float bw = (x1 - x0) * 0.25f;
            const float bh = (y1 - y0) * 0.25f;
            const float area = bw * bh;
            sscale = (area > 0.f) ? 1.f / (16.f * fmaxf(area, 1e-12f)) : 0.f;
        }
    }
    __syncthreads();
    const int wave = t >> 6;
    const int lane = t & 63;
    const int c0 = (bx & 31) * 24 + wave * 6;
    pool_strip<6>(X, b, c0, lane, wx, wy, sscale, feat);
}

template <bool RELU_IN>
__global__ __launch_bounds__(256) void fc_chunk(
    const float* __restrict__ A, const float* __restrict__ bias,
    const float* __restrict__ Wm, float* __restrict__ Out)
{
    __shared__ float As[KC * 68];
    __shared__ float Ws[KC * 68];
    fc_phase<RELU_IN>(A, bias, Wm, Out, As, Ws, threadIdx.x,
                      blockIdx.x * OT, blockIdx.y * KC);
}

__global__ __launch_bounds__(256) void head_kernel(
    const float* __restrict__ x2raw, const float* __restrict__ b2,
    const float* __restrict__ w3, const float* __restrict__ b3,
    float* __restrict__ out)
{
    const int b = blockIdx.x;
    const int t = threadIdx.x;
    float acc = 0.f;
    for (int o = t; o < HID_DIM; o += 256)
        acc += fmaxf(x2raw[(size_t)b * HID_DIM + o] + b2[o], 0.f) * w3[o];
    #pragma unroll
    for (int off = 32; off; off >>= 1) acc += __shfl_down(acc, off);
    __shared__ float r[4];
    if ((t & 63) == 0) r[t >> 6] = acc;
    __syncthreads();
    if (t == 0) out[b] = r[0] + r[1] + r[2] + r[3] + b3[0];
}

extern "C" void kernel_launch(void* const* d_in, const int* in_sizes, int n_in,
                              void* d_out, int out_size, void* d_ws, size_t ws_size,
                              hipStream_t stream) {
    const float* X   = (const float*)d_in[0];
    const float* box = (const float*)d_in[1];
    const float* w1  = (const float*)d_in[2];
    const float* b1  = (const float*)d_in[3];
    const float* w2  = (const float*)d_in[4];
    const float* b2  = (const float*)d_in[5];
    const float* w3  = (const float*)d_in[6];
    const float* b3  = (const float*)d_in[7];
    float* out = (float*)d_out;
    float* ws  = (float*)d_ws;

    void* args[] = {(void*)&X, (void*)&box, (void*)&w1, (void*)&b1,
                    (void*)&w2, (void*)&b2, (void*)&w3, (void*)&b3,
                    (void*)&out, (void*)&ws};
    hipError_t err = hipLaunchCooperativeKernel(
        (const void*)fused_kernel, dim3(NBLK), dim3(256), args, 0, stream);

    if (err != hipSuccess) {
        // fallback: proven 4-kernel chain
        float* feat  = ws;
        float* x1raw = feat + B_DIM * HID_DIM;
        float* x2raw = x1raw + B_DIM * HID_DIM;
        pool_kernel<<<2048, 256, 0, stream>>>(X, box, feat, x1raw);
        fc_chunk<false><<<dim3(HID_DIM / OT, HID_DIM / KC), 256, 0, stream>>>(feat, b1, w1, x1raw);
        fc_chunk<true><<<dim3(HID_DIM / OT, HID_DIM / KC), 256, 0, stream>>>(x1raw, b1, w2, x2raw);
        head_kernel<<<B_DIM, 256, 0, stream>>>(x2raw, b2, w3, b3, out);
    }
}

// Round 8
// 200.911 us; speedup vs baseline: 3.8513x; 3.8513x over previous
//
#include <hip/hip_runtime.h>

#define B_DIM 64
#define C_DIM 768
#define HID_DIM 768
#define PLANE 576          // 24*24 floats per channel plane
#define PLANE4 144         // float4 per plane
#define KC 48              // k-chunk for FC kernels
#define OT 64              // o-tile for FC kernels

__device__ __forceinline__ float hatcdf(float t) {
    // 0 for t<=-1, 0.5(t+1)^2 for -1<t<=0, 1-0.5(1-t)^2 for 0<t<=1, 1 for t>1
    float u = fminf(fmaxf(t, -1.f), 1.f);
    float a = u + 1.f;
    float b = 1.f - u;
    return (t <= 0.f) ? 0.5f * a * a : 1.f - 0.5f * b * b;
}

// K1: feat[b,c] = S_b * sum_{h,w} X[b,c,h,w] * wy[h] * wx[w]
// Weight support is a contiguous rectangle: wx[c] != 0 only for
// c in (x0-1, x1+1), wy[h] != 0 only for h in (y0-1, y1+1). We fetch only
// rows [hlo,hhi] and float4 column groups [c4lo,c4hi] (~25-40% of bytes).
// 2048 blocks x 256 threads; block bx owns b = bx>>5, channels (bx&31)*24..+23,
// each wave 6 planes. Lane = (row8, col8): 8 rows x 8 col4 slots per round.
// First 96 blocks also zero the x1raw/x2raw atomic accumulators.
__global__ __launch_bounds__(256) void pool_kernel(
    const float* __restrict__ X, const float* __restrict__ box,
    float* __restrict__ feat, float* __restrict__ zbuf)
{
    const int t = threadIdx.x;
    const int bx = blockIdx.x;
    if (bx < 96) {  // 96*256 float4 = 98304 floats = x1raw..x2raw
        reinterpret_cast<float4*>(zbuf)[bx * 256 + t] = make_float4(0.f, 0.f, 0.f, 0.f);
    }
    const int b = bx >> 5;

    __shared__ float wx[24], wy[24];
    __shared__ float sscale;
    __shared__ int bnd[4];   // hlo, hhi, c4lo, c4hi
    if (t < 51) {
        const float x0 = box[b * 4 + 0] * 24.f;
        const float y0 = box[b * 4 + 1] * 24.f;
        const float x1 = box[b * 4 + 2] * 24.f;
        const float y1 = box[b * 4 + 3] * 24.f;
        if (t < 24) {
            wx[t] = hatcdf(x1 - (float)t) - hatcdf(x0 - (float)t);
        } else if (t < 48) {
            const int h = t - 24;
            wy[h] = hatcdf(y1 - (float)h) - hatcdf(y0 - (float)h);
        } else if (t == 48) {
            const float bw = (x1 - x0) * 0.25f;
            const float bh = (y1 - y0) * 0.25f;
            const float area = bw * bh;
            sscale = (area > 0.f) ? 1.f / (16.f * fmaxf(area, 1e-12f)) : 0.f;
        } else if (t == 49) {
            // rows with slack; extra edges have wy == 0 (harmless)
            bnd[0] = max(0, (int)y0 - 1);
            bnd[1] = min(23, (int)y1 + 2);
        } else {  // t == 50: column float4 groups
            const int wlo = max(0, (int)x0 - 1);
            const int whi = min(23, (int)x1 + 2);
            bnd[2] = wlo >> 2;
            bnd[3] = whi >> 2;
        }
    }
    __syncthreads();

    const int hlo = bnd[0], hhi = bnd[1];
    const int c4lo = bnd[2], c4hi = bnd[3];

    const int wave = t >> 6;
    const int lane = t & 63;
    const int c0 = (bx & 31) * 24 + wave * 6;
    const float4* __restrict__ P =
        reinterpret_cast<const float4*>(X + ((size_t)b * C_DIM + c0) * PLANE);

    const int r8 = lane >> 3;          // 0..7 : row slot
    const int c4 = c4lo + (lane & 7);  // col4 slot (may be out of range)

    float acc[6];
    #pragma unroll
    for (int p = 0; p < 6; ++p) acc[p] = 0.f;

    if (c4 <= c4hi) {
        const float wx0 = wx[c4 * 4 + 0];
        const float wx1 = wx[c4 * 4 + 1];
        const float wx2 = wx[c4 * 4 + 2];
        const float wx3 = wx[c4 * 4 + 3];
        for (int r = hlo + r8; r <= hhi; r += 8) {
            const float wyr = wy[r];
            const int off = r * 6 + c4;
            #pragma unroll
            for (int p = 0; p < 6; ++p) {
                const float4 v = P[p * PLANE4 + off];
                acc[p] += wyr * (v.x * wx0 + v.y * wx1 + v.z * wx2 + v.w * wx3);
            }
        }
    }

    #pragma unroll
    for (int p = 0; p < 6; ++p) {
        float a = acc[p];
        #pragma unroll
        for (int off = 32; off; off >>= 1) a += __shfl_down(a, off);
        if (lane == 0) feat[(size_t)b * C_DIM + c0 + p] = a * sscale;
    }
}

// K2/K3: Out[b,o] += sum_{k in chunk} A'[b,k] * Wm[k,o],
// A' = RELU_IN ? relu(A + bias) : A.
// grid (HID/OT=12, HID/KC=16) = 192 blocks, 256 threads, 4x4 blocking.
template <bool RELU_IN>
__global__ __launch_bounds__(256) void fc_chunk(
    const float* __restrict__ A, const float* __restrict__ bias,
    const float* __restrict__ Wm, float* __restrict__ Out)
{
    __shared__ float As[KC][68];   // [k][b], padded
    __shared__ float Ws[KC][68];   // [k][o], padded
    const int t = threadIdx.x;
    const int ot = blockIdx.x * OT;
    const int kc = blockIdx.y * KC;

    #pragma unroll
    for (int j = t; j < B_DIM * (KC / 4); j += 256) {
        const int bb = j / (KC / 4);
        const int k4 = (j % (KC / 4)) * 4;
        float4 v = *reinterpret_cast<const float4*>(A + (size_t)bb * HID_DIM + kc + k4);
        if constexpr (RELU_IN) {
            const float4 bv = *reinterpret_cast<const float4*>(bias + kc + k4);
            v.x = fmaxf(v.x + bv.x, 0.f);
            v.y = fmaxf(v.y + bv.y, 0.f);
            v.z = fmaxf(v.z + bv.z, 0.f);
            v.w = fmaxf(v.w + bv.w, 0.f);
        }
        As[k4 + 0][bb] = v.x;
        As[k4 + 1][bb] = v.y;
        As[k4 + 2][bb] = v.z;
        As[k4 + 3][bb] = v.w;
    }
    #pragma unroll
    for (int j = t; j < KC * (OT / 4); j += 256) {
        const int k = j / (OT / 4);
        const int oo = (j % (OT / 4)) * 4;
        const float4 v = *reinterpret_cast<const float4*>(Wm + (size_t)(kc + k) * HID_DIM + ot + oo);
        *reinterpret_cast<float4*>(&Ws[k][oo]) = v;
    }
    __syncthreads();

    const int b0 = (t >> 4) * 4;   // 0..60
    const int o0 = (t & 15) * 4;   // 0..60
    float acc[4][4] = {};
    #pragma unroll 6
    for (int k = 0; k < KC; ++k) {
        const float4 a = *reinterpret_cast<const float4*>(&As[k][b0]);
        const float4 w = *reinterpret_cast<const float4*>(&Ws[k][o0]);
        acc[0][0] += a.x * w.x; acc[0][1] += a.x * w.y; acc[0][2] += a.x * w.z; acc[0][3] += a.x * w.w;
        acc[1][0] += a.y * w.x; acc[1][1] += a.y * w.y; acc[1][2] += a.y * w.z; acc[1][3] += a.y * w.w;
        acc[2][0] += a.z * w.x; acc[2][1] += a.z * w.y; acc[2][2] += a.z * w.z; acc[2][3] += a.z * w.w;
        acc[3][0] += a.w * w.x; acc[3][1] += a.w * w.y; acc[3][2] += a.w * w.z; acc[3][3] += a.w * w.w;
    }
    #pragma unroll
    for (int i = 0; i < 4; ++i)
        #pragma unroll
        for (int j = 0; j < 4; ++j)
            atomicAdd(&Out[(size_t)(b0 + i) * HID_DIM + ot + o0 + j], acc[i][j]);
}

// K4: out[b] = b3 + sum_o relu(x2raw[b,o] + b2[o]) * w3[o]
__global__ __launch_bounds__(256) void head_kernel(
    const float* __restrict__ x2raw, const float* __restrict__ b2,
    const float* __restrict__ w3, const float* __restrict__ b3,
    float* __restrict__ out)
{
    const int b = blockIdx.x;
    const int t = threadIdx.x;
    float acc = 0.f;
    for (int o = t; o < HID_DIM; o += 256)
        acc += fmaxf(x2raw[(size_t)b * HID_DIM + o] + b2[o], 0.f) * w3[o];
    #pragma unroll
    for (int off = 32; off; off >>= 1) acc += __shfl_down(acc, off);
    __shared__ float r[4];
    if ((t & 63) == 0) r[t >> 6] = acc;
    __syncthreads();
    if (t == 0) out[b] = r[0] + r[1] + r[2] + r[3] + b3[0];
}

extern "C" void kernel_launch(void* const* d_in, const int* in_sizes, int n_in,
                              void* d_out, int out_size, void* d_ws, size_t ws_size,
                              hipStream_t stream) {
    const float* X   = (const float*)d_in[0];
    const float* box = (const float*)d_in[1];
    const float* w1  = (const float*)d_in[2];
    const float* b1  = (const float*)d_in[3];
    const float* w2  = (const float*)d_in[4];
    const float* b2  = (const float*)d_in[5];
    const float* w3  = (const float*)d_in[6];
    const float* b3  = (const float*)d_in[7];
    float* out = (float*)d_out;

    float* feat  = (float*)d_ws;                 // 64*768
    float* x1raw = feat + B_DIM * HID_DIM;       // 64*768 (zeroed by K1)
    float* x2raw = x1raw + B_DIM * HID_DIM;      // 64*768 (zeroed by K1)

    pool_kernel<<<2048, 256, 0, stream>>>(X, box, feat, x1raw);
    fc_chunk<false><<<dim3(HID_DIM / OT, HID_DIM / KC), 256, 0, stream>>>(feat, b1, w1, x1raw);
    fc_chunk<true><<<dim3(HID_DIM / OT, HID_DIM / KC), 256, 0, stream>>>(x1raw, b1, w2, x2raw);
    head_kernel<<<B_DIM, 256, 0, stream>>>(x2raw, b2, w3, b3, out);
}